// Round 2
// baseline (15611.092 us; speedup 1.0000x reference)
//
#include <hip/hip_runtime.h>
#include <math.h>

#define TT 2048
#define BB 32
#define DD 512
#define GB 8           // batch groups (4 batches each)
#define GS 32          // slices per group (16 hidden units each)
#define NBLK (GB*GS)   // 256 blocks = 1 per CU -> co-residency guaranteed
#define NTHR 512
#define BPG (BB/GB)    // 4 batches per group
#define HU 16
#define ROWS 64        // group h elements written per block to out (64 of 2048)
#define CHP 68         // padded chunk stride (68%32=4, 272B keeps 16B alignment)

typedef unsigned long long ull;

// Coherence-point (MALL) accessors: agent-scope relaxed atomics -> global_load/
// store ... sc0 sc1, bypassing L1 and the non-coherent per-XCD L2. 8-byte words
// carry (h_bits, step_tag) so the payload IS the flag: one MALL round trip from
// producer store to consumer detect, no fence, no vmcnt, no flag array.
__device__ __forceinline__ ull ld_mall64(const ull* p) {
  return __hip_atomic_load((ull*)p, __ATOMIC_RELAXED, __HIP_MEMORY_SCOPE_AGENT);
}
__device__ __forceinline__ void st_mall64(ull* p, ull v) {
  __hip_atomic_store(p, v, __ATOMIC_RELAXED, __HIP_MEMORY_SCOPE_AGENT);
}
__device__ __forceinline__ float sigm(float v) {
  return __builtin_amdgcn_rcpf(1.0f + __expf(-v));
}
__device__ __forceinline__ float tanh_fast(float v) {
  return 2.0f * sigm(2.0f * v) - 1.0f;   // exact identity tanh(x)=2*sigmoid(2x)-1
}

// Persistent LSTM. 256 blocks x 512 threads, 1 block/CU. Per thread: 2 gate rows
// x (32-wide Wih chunk + 32-wide Whh chunk) in VGPRs. Row mapping puts (i,g) and
// (f,o) rows of a unit in lanes tid^16 of the SAME wave, so the cell update is
// in-wave (no gates LDS, no 3rd barrier). Per step: x-dot (h-independent) runs
// while producers' stores propagate; then poll self-tagged h payload, h-dot,
// kc-reduce, shfl(16) gather, cell update in registers, publish packed h.
__global__ __launch_bounds__(NTHR, 2)
void lstm_persistent(const float* __restrict__ x,
                     const float* __restrict__ Wih,
                     const float* __restrict__ Whh,
                     const float* __restrict__ bih,
                     const float* __restrict__ bhh,
                     float* __restrict__ out,
                     ull* __restrict__ Hpk)      // [GB][2][BPG][DD] packed (h,tag)
{
  __shared__ float in_buf[BPG][16][CHP];   // [batch][row][64+pad]; rows 0-7 = x, 8-15 = h

  const int tid = threadIdx.x;
  const int blk = blockIdx.x;
  const int g   = blk & 7;    // group (blk%8 -> same XCD under round-robin; perf only)
  const int s   = blk >> 3;   // slice 0..31
  const int j   = tid >> 4;   // 0..31 row-pair id
  const int kc  = tid & 15;   // 0..15 k-chunk (32 floats each, per weight half)
  const int u0  = s * HU;
  const int gb0 = g * BPG;
  const int v   = j >> 1;     // hidden unit 0..15 within slice
  const int gl  = j & 1;      // 0: rows (i,g)   1: rows (f,o)
  const int row0 = gl * DD + u0 + v;        // gate i or f
  const int row1 = (gl + 2) * DD + u0 + v;  // gate g or o

  // --- per-thread weights: 2 rows x 32 floats from Wih + 32 floats from Whh ---
  float4 w0x[8], w1x[8], w0h[8], w1h[8];
  {
    const float4* p0x = (const float4*)(Wih + (size_t)row0 * DD + kc * 32);
    const float4* p1x = (const float4*)(Wih + (size_t)row1 * DD + kc * 32);
    const float4* p0h = (const float4*)(Whh + (size_t)row0 * DD + kc * 32);
    const float4* p1h = (const float4*)(Whh + (size_t)row1 * DD + kc * 32);
    #pragma unroll
    for (int q = 0; q < 8; ++q) {
      w0x[q] = p0x[q]; w1x[q] = p1x[q]; w0h[q] = p0h[q]; w1h[q] = p1h[q];
    }
  }
  // biases for the 4 gates of unit v (meaningful on even-j lanes; all compute)
  const float b_i = bih[0*DD + u0 + v] + bhh[0*DD + u0 + v];
  const float b_f = bih[1*DD + u0 + v] + bhh[1*DD + u0 + v];
  const float b_g = bih[2*DD + u0 + v] + bhh[2*DD + u0 + v];
  const float b_o = bih[3*DD + u0 + v] + bhh[3*DD + u0 + v];

  float c_st[BPG] = {0.f, 0.f, 0.f, 0.f};   // cell state in registers (even-j lanes own)

  const int sb   = tid >> 7;            // staging batch 0..3
  const int kpos = (tid & 127) * 4;     // staging position 0..508
  const float* xg = x + (size_t)(gb0 + sb) * TT * DD + kpos;
  float4 vx = *(const float4*)xg;       // x(0) prefetched

  for (int t = 0; t < TT; ++t) {
    // --- stage x(t) (prefetched last iter); prefetch x(t+1) ---
    *(float4*)&in_buf[sb][kpos >> 6][kpos & 63] = vx;
    {
      int tn = (t + 1 < TT) ? t + 1 : t;   // clamp avoids OOB on last step
      vx = *(const float4*)(xg + (size_t)tn * DD);
    }
    __syncthreads();   // A: x staged (also orders prev-step h-region reads vs h-stage below)

    // --- x-part dots (h-independent; overlaps producers' publish latency) ---
    float rx0[BPG], rx1[BPG];
    #pragma unroll
    for (int b = 0; b < BPG; ++b) {
      const float4* vp = (const float4*)&in_buf[b][kc >> 1][(kc & 1) * 32];
      float4 a0 = {0,0,0,0}, a1 = {0,0,0,0};
      #pragma unroll
      for (int q = 0; q < 8; ++q) {
        float4 vv = vp[q];
        a0.x += vv.x * w0x[q].x; a0.y += vv.y * w0x[q].y;
        a0.z += vv.z * w0x[q].z; a0.w += vv.w * w0x[q].w;
        a1.x += vv.x * w1x[q].x; a1.y += vv.y * w1x[q].y;
        a1.z += vv.z * w1x[q].z; a1.w += vv.w * w1x[q].w;
      }
      rx0[b] = (a0.x + a0.y) + (a0.z + a0.w);
      rx1[b] = (a1.x + a1.y) + (a1.z + a1.w);
    }

    // --- poll + stage h(t-1): payload tags are the synchronization ---
    if (t == 0) {
      float4 z = {0, 0, 0, 0};
      *(float4*)&in_buf[sb][8 + (kpos >> 6)][kpos & 63] = z;
    } else {
      const ull* hp = Hpk + (size_t)(g * 2 + ((t - 1) & 1)) * BPG * DD + sb * DD + kpos;
      const unsigned tt = (unsigned)t;   // producer step t-1 wrote tag t
      ull v0, v1, v2, v3;
      int guard = 0;
      for (;;) {
        v0 = ld_mall64(hp + 0); v1 = ld_mall64(hp + 1);
        v2 = ld_mall64(hp + 2); v3 = ld_mall64(hp + 3);
        if ((unsigned)(v0 >> 32) == tt && (unsigned)(v1 >> 32) == tt &&
            (unsigned)(v2 >> 32) == tt && (unsigned)(v3 >> 32) == tt) break;
        if (++guard > (1 << 22)) break;   // fail loud-ish, never hang the harness
        __builtin_amdgcn_s_sleep(1);
      }
      float4 hv;
      hv.x = __uint_as_float((unsigned)v0); hv.y = __uint_as_float((unsigned)v1);
      hv.z = __uint_as_float((unsigned)v2); hv.w = __uint_as_float((unsigned)v3);
      *(float4*)&in_buf[sb][8 + (kpos >> 6)][kpos & 63] = hv;
    }
    __syncthreads();   // B: h staged

    // --- write h(t-1) to out from the staged copy (off critical path) ---
    if (t > 0 && tid < ROWS) {
      int flat = s * 64 + tid;           // 0..2047 over group's [BPG][DD]
      int ob = flat >> 9, okp = flat & 511;
      out[((size_t)(gb0 + ob) * TT + (t - 1)) * DD + okp] =
          in_buf[ob][8 + (okp >> 6)][okp & 63];
    }

    // --- h-part dots + combine ---
    float r0[BPG], r1[BPG];
    #pragma unroll
    for (int b = 0; b < BPG; ++b) {
      const float4* vp = (const float4*)&in_buf[b][8 + (kc >> 1)][(kc & 1) * 32];
      float4 a0 = {0,0,0,0}, a1 = {0,0,0,0};
      #pragma unroll
      for (int q = 0; q < 8; ++q) {
        float4 vv = vp[q];
        a0.x += vv.x * w0h[q].x; a0.y += vv.y * w0h[q].y;
        a0.z += vv.z * w0h[q].z; a0.w += vv.w * w0h[q].w;
        a1.x += vv.x * w1h[q].x; a1.y += vv.y * w1h[q].y;
        a1.z += vv.z * w1h[q].z; a1.w += vv.w * w1h[q].w;
      }
      r0[b] = rx0[b] + (a0.x + a0.y) + (a0.z + a0.w);
      r1[b] = rx1[b] + (a1.x + a1.y) + (a1.z + a1.w);
    }
    // reduce across the 16 kc lanes; all 4 batches interleaved for ILP
    #pragma unroll
    for (int m = 1; m < 16; m <<= 1) {
      #pragma unroll
      for (int b = 0; b < BPG; ++b) {
        r0[b] += __shfl_xor(r0[b], m, 64);
        r1[b] += __shfl_xor(r1[b], m, 64);
      }
    }

    // --- in-wave cell update: lanes tid^16 hold (f,o) for this lane's (i,g) ---
    ull* hd = Hpk + (size_t)(g * 2 + (t & 1)) * BPG * DD + u0 + v;
    const unsigned tagv = (unsigned)(t + 1);
    #pragma unroll
    for (int b = 0; b < BPG; ++b) {
      float f_in = __shfl_xor(r0[b], 16, 64);
      float o_in = __shfl_xor(r1[b], 16, 64);
      float ig = sigm(r0[b] + b_i);
      float fg = sigm(f_in + b_f);
      float gg = tanh_fast(r1[b] + b_g);
      float og = sigm(o_in + b_o);
      float c  = fg * c_st[b] + ig * gg;
      c_st[b] = c;
      float h  = og * tanh_fast(c);
      if ((tid & 31) == 0)   // gl==0 && kc==0: owning lane for unit v, all 4 gates
        st_mall64(hd + b * DD, ((ull)tagv << 32) | (ull)__float_as_uint(h));
    }
    // No 3rd barrier: x-region writes at next loop-top are protected by B (all
    // x-dot reads done before B); h-region writes are after A(t+1).
  }

  // --- emit final timestep h(T-1) straight from the payload ---
  if (tid < ROWS) {
    int flat = s * 64 + tid;
    int ob = flat >> 9, okp = flat & 511;
    const ull* p = Hpk + (size_t)(g * 2 + ((TT - 1) & 1)) * BPG * DD + ob * DD + okp;
    ull vv;
    int guard = 0;
    for (;;) {
      vv = ld_mall64(p);
      if ((unsigned)(vv >> 32) == (unsigned)TT) break;
      if (++guard > (1 << 22)) break;
      __builtin_amdgcn_s_sleep(1);
    }
    out[((size_t)(gb0 + ob) * TT + (TT - 1)) * DD + okp] = __uint_as_float((unsigned)vv);
  }
}

extern "C" void kernel_launch(void* const* d_in, const int* in_sizes, int n_in,
                              void* d_out, int out_size, void* d_ws, size_t ws_size,
                              hipStream_t stream) {
  const float* x   = (const float*)d_in[0];
  const float* Wih = (const float*)d_in[1];
  const float* Whh = (const float*)d_in[2];
  const float* bih = (const float*)d_in[3];
  const float* bhh = (const float*)d_in[4];
  float* out = (float*)d_out;

  // ws layout: Hpk [8][2][4][512] x 8B = 256 KB. No memset needed: consumers use
  // exact-equality tag checks (poison 0xAAAAAAAA and any previous-run leftover
  // can never equal the expected step tag before its producer writes it).
  ull* Hpk = (ull*)d_ws;

  lstm_persistent<<<dim3(NBLK), dim3(NTHR), 0, stream>>>(x, Wih, Whh, bih, bhh,
                                                         out, Hpk);
}